// Round 6
// baseline (428.029 us; speedup 1.0000x reference)
//
#include <hip/hip_runtime.h>

#define N 8192
#define DIN 512
#define DOUT 256
#define ALPHA 0.2f
#define NEG_INF -9.0e15f

typedef __attribute__((ext_vector_type(8))) short bf16x8;
typedef __attribute__((ext_vector_type(4))) float f32x4;
typedef __attribute__((ext_vector_type(4))) int   i32x4;

__device__ __forceinline__ unsigned f2bf_u(float f) {
    unsigned u = __builtin_bit_cast(unsigned, f);
    return (u + 0x7fffu + ((u >> 16) & 1u)) >> 16;   // RNE bf16
}
__device__ __forceinline__ unsigned pack2bf(float lo, float hi) {
    return f2bf_u(lo) | (f2bf_u(hi) << 16);
}
__device__ __forceinline__ float bf2f(ushort u) {
    return __builtin_bit_cast(float, (unsigned)u << 16);
}
union U4BF8 { uint4 u; bf16x8 v; };

__device__ __forceinline__ void async_copy16(const ushort* g, ushort* l) {
    __builtin_amdgcn_global_load_lds(
        (const __attribute__((address_space(1))) unsigned*)g,
        (__attribute__((address_space(3))) unsigned*)l, 16, 0, 0);
}

// Kernel 0: W fp32 [512][256] -> WB bf16 in MFMA-B layout ((k>>3)*256+c)*8+(k&7).
__global__ __launch_bounds__(256) void wb_kernel(const float* __restrict__ W,
                                                 ushort* __restrict__ WB) {
    const int g = blockIdx.x * 256 + threadIdx.x;   // 64*256 = 16384
    const int c = g & 255, k8 = g >> 8;
    const float* wp = W + (size_t)(k8 * 8) * DOUT + c;
    U4BF8 o;
    o.u.x = pack2bf(wp[0 * DOUT], wp[1 * DOUT]);
    o.u.y = pack2bf(wp[2 * DOUT], wp[3 * DOUT]);
    o.u.z = pack2bf(wp[4 * DOUT], wp[5 * DOUT]);
    o.u.w = pack2bf(wp[6 * DOUT], wp[7 * DOUT]);
    *(uint4*)(WB + (size_t)g * 8) = o.u;
}

// Kernel 1: h = X@W + b via MFMA, split-K across 4 waves (unchanged).
__global__ __launch_bounds__(256) void h_kernel(
        const float* __restrict__ X, const ushort* __restrict__ WB,
        const float* __restrict__ bvec, const float* __restrict__ a,
        ushort* __restrict__ hB, float* __restrict__ el, float* __restrict__ er)
{
    __shared__ float red[4][64][65];
    __shared__ float elr[2][4][16];
    const int t = threadIdx.x;
    const int w = t >> 6, l = t & 63, q = l >> 4, n = l & 15;
    const int i0 = blockIdx.x * 16;
    f32x4 acc[16];
    #pragma unroll
    for (int ct = 0; ct < 16; ++ct) acc[ct] = (f32x4){0.f, 0.f, 0.f, 0.f};
    const float* xp = X + (size_t)(i0 + n) * DIN + q * 8;

    #pragma unroll
    for (int ks = 0; ks < 4; ++ks) {
        const int k0 = w * 128 + ks * 32;
        const float4 x0 = *(const float4*)(xp + k0);
        const float4 x1 = *(const float4*)(xp + k0 + 4);
        U4BF8 pa;
        pa.u.x = pack2bf(x0.x, x0.y); pa.u.y = pack2bf(x0.z, x0.w);
        pa.u.z = pack2bf(x1.x, x1.y); pa.u.w = pack2bf(x1.z, x1.w);
        const ushort* wbp = WB + ((k0 >> 3) + q) * 2048 + n * 8;
        bf16x8 bfr[16];
        #pragma unroll
        for (int ct = 0; ct < 16; ++ct) bfr[ct] = *(const bf16x8*)(wbp + ct * 128);
        #pragma unroll
        for (int ct = 0; ct < 16; ++ct)
            acc[ct] = __builtin_amdgcn_mfma_f32_16x16x32_bf16(pa.v, bfr[ct], acc[ct], 0, 0, 0);
    }
    #pragma unroll
    for (int ct = 0; ct < 16; ++ct)
        #pragma unroll
        for (int r = 0; r < 4; ++r) red[w][l][ct * 4 + r] = acc[ct][r];
    __syncthreads();

    float pl[4] = {0.f, 0.f, 0.f, 0.f}, pr[4] = {0.f, 0.f, 0.f, 0.f};
    const int hbase = (blockIdx.x * 2 + (q >> 1)) * 2048 + n * 8 + (q & 1) * 4;
    #pragma unroll
    for (int c2 = 0; c2 < 4; ++c2) {
        const int ct = w * 4 + c2;
        const float bb = bvec[ct * 16 + n];
        const float al = a[ct * 16 + n];
        const float ar = a[DOUT + ct * 16 + n];
        float v[4];
        #pragma unroll
        for (int r = 0; r < 4; ++r) {
            v[r] = red[0][l][ct * 4 + r] + red[1][l][ct * 4 + r]
                 + red[2][l][ct * 4 + r] + red[3][l][ct * 4 + r] + bb;
            pl[r] += v[r] * al;
            pr[r] += v[r] * ar;
        }
        ushort4 hp;
        hp.x = (ushort)f2bf_u(v[0]); hp.y = (ushort)f2bf_u(v[1]);
        hp.z = (ushort)f2bf_u(v[2]); hp.w = (ushort)f2bf_u(v[3]);
        *(ushort4*)&hB[hbase + ct * 128] = hp;
    }
    #pragma unroll
    for (int r = 0; r < 4; ++r) {
        #pragma unroll
        for (int off = 1; off < 16; off <<= 1) {
            pl[r] += __shfl_xor(pl[r], off);
            pr[r] += __shfl_xor(pr[r], off);
        }
    }
    if (n == 0) {
        #pragma unroll
        for (int r = 0; r < 4; ++r) {
            elr[0][w][q * 4 + r] = pl[r];
            elr[1][w][q * 4 + r] = pr[r];
        }
    }
    __syncthreads();
    if (t < 16) {
        el[i0 + t] = elr[0][0][t] + elr[0][1][t] + elr[0][2][t] + elr[0][3][t];
        er[i0 + t] = elr[1][0][t] + elr[1][1][t] + elr[1][2][t] + elr[1][3][t];
    }
}

// Kernel 2: attention partials. Block = 128 rows x 2048 j (j-quarter).
// grid 256 = 64 rb x 4 jq. Wave w: rows w*16..+16, 128-j steps (16).
// adj loads PLAIN (LLC-retained) and issued FIRST each step; hB tiles
// double-buffered via global_load_lds; partials stored bf16 (nontemporal).
__global__ __launch_bounds__(512, 1) void attn_kernel(
        const int* __restrict__ adj, const float* __restrict__ el,
        const float* __restrict__ er, const float* __restrict__ ab,
        const ushort* __restrict__ hB, ushort* __restrict__ pout,
        float* __restrict__ plsum)
{
    __shared__ ushort stage[2][32768];   // 2 x 64 KB
    __shared__ float ers[2048];          // 8 KB
    const int t = threadIdx.x;
    const int w = t >> 6, l = t & 63, q = l >> 4, n = l & 15;
    const int rb = blockIdx.x >> 2, jq = blockIdx.x & 3;
    const int j0 = jq * 2048;
    const int row = rb * 128 + w * 16 + n;
    const float elm = el[row] + ab[0];
    const int* alp = adj + (size_t)row * N + j0 + q * 8;

    f32x4 acc[16];
    #pragma unroll
    for (int ct = 0; ct < 16; ++ct) acc[ct] = (f32x4){0.f, 0.f, 0.f, 0.f};
    float lsum = 0.f;

    // prologue: er quarter -> LDS; adj regs for step 0; hB step-0 tile -> stage[0]
    *(float4*)&ers[t * 4] = *(const float4*)&er[j0 + t * 4];
    i32x4 a[8];
    #pragma unroll
    for (int kg = 0; kg < 4; ++kg) {
        a[2 * kg]     = *(const i32x4*)(alp + kg * 32);
        a[2 * kg + 1] = *(const i32x4*)(alp + kg * 32 + 4);
    }
    {
        const ushort* g = hB + (size_t)j0 * 256 + t * 8;
        ushort* lb = &stage[0][t * 8];
        #pragma unroll
        for (int i = 0; i < 8; ++i) async_copy16(g + i * 4096, lb + i * 4096);
    }

    for (int s = 0; s < 16; ++s) {
        __syncthreads();                 // stage[s&1] + adj regs for s ready
        // snapshot step-s adj regs, then issue step s+1 HBM traffic FIRST
        i32x4 aa[8];
        #pragma unroll
        for (int i = 0; i < 8; ++i) aa[i] = a[i];
        if (s < 15) {
            const int* ap = alp + (s + 1) * 128;
            #pragma unroll
            for (int kg = 0; kg < 4; ++kg) {
                a[2 * kg]     = *(const i32x4*)(ap + kg * 32);
                a[2 * kg + 1] = *(const i32x4*)(ap + kg * 32 + 4);
            }
            const ushort* g = hB + (size_t)(j0 + (s + 1) * 128) * 256 + t * 8;
            ushort* lb = &stage[(s + 1) & 1][t * 8];
            #pragma unroll
            for (int i = 0; i < 8; ++i) async_copy16(g + i * 4096, lb + i * 4096);
        }
        // A-fragments: 4 K-groups x 8 j per lane
        U4BF8 pa[4];
        #pragma unroll
        for (int kg = 0; kg < 4; ++kg) {
            const float4 e0 = *(const float4*)&ers[s * 128 + kg * 32 + q * 8];
            const float4 e1 = *(const float4*)&ers[s * 128 + kg * 32 + q * 8 + 4];
            const i32x4 a0 = aa[2 * kg], a1 = aa[2 * kg + 1];
            float v, p0, p1, p2, p3, p4, p5, p6, p7;
            v = elm + e0.x; v = fmaxf(v, ALPHA * v); p0 = __expf(a0.x > 0 ? v : NEG_INF);
            v = elm + e0.y; v = fmaxf(v, ALPHA * v); p1 = __expf(a0.y > 0 ? v : NEG_INF);
            v = elm + e0.z; v = fmaxf(v, ALPHA * v); p2 = __expf(a0.z > 0 ? v : NEG_INF);
            v = elm + e0.w; v = fmaxf(v, ALPHA * v); p3 = __expf(a0.w > 0 ? v : NEG_INF);
            v = elm + e1.x; v = fmaxf(v, ALPHA * v); p4 = __expf(a1.x > 0 ? v : NEG_INF);
            v = elm + e1.y; v = fmaxf(v, ALPHA * v); p5 = __expf(a1.y > 0 ? v : NEG_INF);
            v = elm + e1.z; v = fmaxf(v, ALPHA * v); p6 = __expf(a1.z > 0 ? v : NEG_INF);
            v = elm + e1.w; v = fmaxf(v, ALPHA * v); p7 = __expf(a1.w > 0 ? v : NEG_INF);
            lsum += p0 + p1 + p2 + p3 + p4 + p5 + p6 + p7;
            pa[kg].u.x = pack2bf(p0, p1); pa[kg].u.y = pack2bf(p2, p3);
            pa[kg].u.z = pack2bf(p4, p5); pa[kg].u.w = pack2bf(p6, p7);
        }
        #pragma unroll
        for (int kg = 0; kg < 4; ++kg) {
            const ushort* sb = &stage[s & 1][(kg * 4 + q) * 2048 + n * 8];
            #pragma unroll
            for (int ct = 0; ct < 16; ++ct) {
                const bf16x8 bf = *(const bf16x8*)(sb + ct * 128);
                acc[ct] = __builtin_amdgcn_mfma_f32_16x16x32_bf16(pa[kg].v, bf, acc[ct], 0, 0, 0);
            }
        }
    }

    // row sums: reduce across the 4 q-groups holding row n
    lsum += __shfl_xor(lsum, 16);
    lsum += __shfl_xor(lsum, 32);
    if (l < 16) plsum[(size_t)jq * N + row] = lsum;

    // unnormalized partial tile (bf16): rows rb*128 + w*16 + q*4+r, col ct*16+n
    ushort* pb = pout + ((size_t)jq * N + rb * 128 + w * 16 + q * 4) * 256 + n;
    #pragma unroll
    for (int ct = 0; ct < 16; ++ct)
        #pragma unroll
        for (int r = 0; r < 4; ++r)
            __builtin_nontemporal_store((ushort)f2bf_u(acc[ct][r]),
                                        pb + (size_t)r * 256 + ct * 16);
}

// Kernel 3: combine bf16 j-quarter partials + normalize. grid 2048 x 256.
__global__ __launch_bounds__(256) void combine_kernel(
        const ushort* __restrict__ pout, const float* __restrict__ plsum,
        float* __restrict__ out)
{
    const int t = threadIdx.x;
    const int row = blockIdx.x * 4 + (t >> 6);
    const int c = (t & 63) * 4;
    const size_t idx = (size_t)row * 256 + c;
    const size_t qs = (size_t)N * 256;
    const ushort4 v0 = *(const ushort4*)&pout[idx];
    const ushort4 v1 = *(const ushort4*)&pout[idx + qs];
    const ushort4 v2 = *(const ushort4*)&pout[idx + 2 * qs];
    const ushort4 v3 = *(const ushort4*)&pout[idx + 3 * qs];
    const float li = 1.0f / (plsum[row] + plsum[N + row]
                           + plsum[2 * N + row] + plsum[3 * N + row]);
    float4 o;
    o.x = (bf2f(v0.x) + bf2f(v1.x) + bf2f(v2.x) + bf2f(v3.x)) * li;
    o.y = (bf2f(v0.y) + bf2f(v1.y) + bf2f(v2.y) + bf2f(v3.y)) * li;
    o.z = (bf2f(v0.z) + bf2f(v1.z) + bf2f(v2.z) + bf2f(v3.z)) * li;
    o.w = (bf2f(v0.w) + bf2f(v1.w) + bf2f(v2.w) + bf2f(v3.w)) * li;
    *(float4*)&out[idx] = o;
}

extern "C" void kernel_launch(void* const* d_in, const int* in_sizes, int n_in,
                              void* d_out, int out_size, void* d_ws, size_t ws_size,
                              hipStream_t stream) {
    const int*   adj = (const int*)  d_in[0];
    const float* X   = (const float*)d_in[1];
    const float* W   = (const float*)d_in[2];
    const float* b   = (const float*)d_in[3];
    const float* a   = (const float*)d_in[4];
    const float* ab  = (const float*)d_in[5];
    float* out = (float*)d_out;

    ushort* hB    = (ushort*)d_ws;                        // 4 MB
    ushort* WB    = hB + (size_t)N * DOUT;                // 256 KB
    float*  el    = (float*)(WB + (size_t)DIN * DOUT);    // 32 KB
    float*  er    = el + N;                               // 32 KB
    float*  plsum = er + N;                               // 4*N fp32 = 128 KB
    ushort* pout  = (ushort*)(plsum + 4 * N);             // 4*N*256 bf16 = 16 MB

    wb_kernel<<<dim3(64), dim3(256), 0, stream>>>(W, WB);
    h_kernel<<<dim3(N / 16), dim3(256), 0, stream>>>(X, WB, b, a, hB, el, er);
    attn_kernel<<<dim3(256), dim3(512), 0, stream>>>(adj, el, er, ab, hB, pout, plsum);
    combine_kernel<<<dim3(N / 4), dim3(256), 0, stream>>>(pout, plsum, out);
}